// Round 11
// baseline (269.895 us; speedup 1.0000x reference)
//
#include <hip/hip_runtime.h>
#include <hip/hip_bf16.h>

// Problem constants
#define S     2048
#define D     1024
#define NH    8
#define NKV   2
#define HD    128
#define WS_   64
#define E_    16
#define HDIM  512
#define TOPK  2
#define NTOK  S
#define NSLOT (S*TOPK)         // 4096
#define QKV_M (D + 2*NKV*HD)   // 1536 fused q|k|v columns
#define KOFF  D                // 1024
#define VOFF  (D + NKV*HD)     // 1280
#define QB    4                // queries per attention block
#define WROWS (QB + WS_ - 1)   // 67 key rows per window
#define KPITCH 69              // KT key pitch (float4 units, odd)
#define NTILES 80              // max MoE row-tiles: sum ceil(r_e/64) <= 79
#define EPAD  4096             // per-expert slot-pad (max 2048 actually)

typedef __attribute__((ext_vector_type(8))) short bf16x8;
typedef __attribute__((ext_vector_type(4))) float floatx4;

__device__ inline short f2bf(float f) {
    __hip_bfloat16 b = __float2bfloat16(f);
    return *reinterpret_cast<short*>(&b);
}

// ---------------------------------------------------------------------------
// All weight prep + attention pre-norm in ONE launch.
// Transpose tiles are 64(k) x 32(m): writes are 128B full-line segments.
// router_w stored INTERLEAVED (R10-proven): per-instruction router load is
// one contiguous 1 KB line.
// ---------------------------------------------------------------------------
__global__ __launch_bounds__(256) void tconv_all(
    const float* __restrict__ wq, const float* __restrict__ wk,
    const float* __restrict__ wv, const float* __restrict__ wo,
    const float* __restrict__ w1, const float* __restrict__ w2,
    const float* __restrict__ bq, const float* __restrict__ bk,
    const float* __restrict__ bv, const float* __restrict__ router_w,
    short* __restrict__ wqkvT, short* __restrict__ woT,
    short* __restrict__ w1T, short* __restrict__ w2T,
    float* __restrict__ bqkv, float* __restrict__ rwT,
    const float* __restrict__ x, const float* __restrict__ norm1_w,
    short* __restrict__ h_bf, int* __restrict__ ecur)
{
    int id = blockIdx.x;
    if (id >= 9511) {                        // 2048 rmsnorm blocks
        int row = id - 9511, t = threadIdx.x;
        float4 v = ((const float4*)(x + (size_t)row * D))[t];
        float ss = v.x*v.x + v.y*v.y + v.z*v.z + v.w*v.w;
        #pragma unroll
        for (int off = 32; off; off >>= 1) ss += __shfl_xor(ss, off, 64);
        __shared__ float red[4];
        if ((t & 63) == 0) red[t >> 6] = ss;
        __syncthreads();
        float total = red[0] + red[1] + red[2] + red[3];
        float scale = rsqrtf(total * (1.0f / (float)D) + 1e-6f);
        float4 wv4 = ((const float4*)norm1_w)[t];
        short4 ob;
        ob.x = f2bf(v.x * scale * wv4.x); ob.y = f2bf(v.y * scale * wv4.y);
        ob.z = f2bf(v.z * scale * wv4.z); ob.w = f2bf(v.w * scale * wv4.w);
        ((short4*)(h_bf + (size_t)row * D))[t] = ob;
        return;
    }
    if (id == 9510) {                        // zero expert cursors (16x32 ints)
        int t = threadIdx.x;
        ecur[t] = 0; ecur[t + 256] = 0;
        return;
    }
    if (id >= 9478) {                        // 32 router_w interleave blocks
        int ky = id - 9478;                  // 0..31
        int t = threadIdx.x;
        int r = t >> 4, c = t & 15;
        int k0 = ky * 32;
        int k1 = k0 + r, k2 = k0 + r + 16;
        rwT[((k1 >> 2) << 6) + (c << 2) + (k1 & 3)] = router_w[k1 * E_ + c];
        rwT[((k2 >> 2) << 6) + (c << 2) + (k2 & 3)] = router_w[k2 * E_ + c];
        return;
    }
    if (id >= 9472) {                        // 6 bias-concat blocks
        int t = (id - 9472) * 256 + threadIdx.x;
        if (t < D) bqkv[t] = bq[t];
        else if (t < VOFF) bqkv[t] = bk[t - D];
        else bqkv[t] = bv[t - VOFF];
        return;
    }
    const float* in; short* outp; int K, M, mx, ky;
    if (id < 512)       { in = wq; outp = wqkvT;                  K = D; M = D;   int l = id;        mx = l & 31; ky = l >> 5; }
    else if (id < 640)  { in = wk; outp = wqkvT + (size_t)KOFF*D; K = D; M = 256; int l = id - 512;  mx = l & 7;  ky = l >> 3; }
    else if (id < 768)  { in = wv; outp = wqkvT + (size_t)VOFF*D; K = D; M = 256; int l = id - 640;  mx = l & 7;  ky = l >> 3; }
    else if (id < 1280) { in = wo; outp = woT;                    K = D; M = D;   int l = id - 768;  mx = l & 31; ky = l >> 5; }
    else if (id < 5376) { int l = id - 1280; int e = l >> 8; int r = l & 255;
                          in = w1 + (size_t)e * D * HDIM; outp = w1T + (size_t)e * D * HDIM;
                          K = D; M = HDIM; mx = r & 15; ky = r >> 4; }
    else                { int l = id - 5376; int e = l >> 8; int r = l & 255;
                          in = w2 + (size_t)e * D * HDIM; outp = w2T + (size_t)e * D * HDIM;
                          K = HDIM; M = D; mx = r & 31; ky = r >> 5; }
    __shared__ float tile[64][33];
    int t = threadIdx.x;
    int k0 = ky * 64, m0 = mx * 32;
    {   // read: 64 rows x 32 floats; 8 threads/row -> 128B segments
        int r = t >> 3, c4 = (t & 7) * 4;
        float4 v0 = *(const float4*)&in[(size_t)(k0 + r) * M + m0 + c4];
        float4 v1 = *(const float4*)&in[(size_t)(k0 + r + 32) * M + m0 + c4];
        tile[r][c4 + 0] = v0.x; tile[r][c4 + 1] = v0.y;
        tile[r][c4 + 2] = v0.z; tile[r][c4 + 3] = v0.w;
        tile[r + 32][c4 + 0] = v1.x; tile[r + 32][c4 + 1] = v1.y;
        tile[r + 32][c4 + 2] = v1.z; tile[r + 32][c4 + 3] = v1.w;
    }
    __syncthreads();
    {   // write: 32 rows x 64 shorts; 16 threads/row -> 128B segments
        int mr = t >> 4, kc4 = (t & 15) * 4;
        short4 o0, o1;
        o0.x = f2bf(tile[kc4 + 0][mr]);      o0.y = f2bf(tile[kc4 + 1][mr]);
        o0.z = f2bf(tile[kc4 + 2][mr]);      o0.w = f2bf(tile[kc4 + 3][mr]);
        o1.x = f2bf(tile[kc4 + 0][mr + 16]); o1.y = f2bf(tile[kc4 + 1][mr + 16]);
        o1.z = f2bf(tile[kc4 + 2][mr + 16]); o1.w = f2bf(tile[kc4 + 3][mr + 16]);
        *(short4*)&outp[(size_t)(m0 + mr) * K + k0 + kc4] = o0;
        *(short4*)&outp[(size_t)(m0 + mr + 16) * K + k0 + kc4] = o1;
    }
}

// ---------------------------------------------------------------------------
// bf16 MFMA GEMM: 64x64 tile, BK=64, TRIPLE-buffered LDS (48 KB),
// global_load_lds width=16 staging issued TWO tiles ahead, raw s_barrier
// with COUNTED s_waitcnt vmcnt(4) (T4). Epilogue operands prefetched into
// registers BEFORE the loop. XOR involution swizzle source+read.
// V<2: XCD-aware block swizzle (T1). MFMA accumulation order identical.
// V=0: C fp32 (QKV)            V=1: +bias+res (WO->x1)
// V=2: MoE1 silu->bf16, A-rows via tokpad[e][local]; tile-map grid
// V=3: MoE2 atomic out[tok] += gate*(val+bias); tile-map grid
// ---------------------------------------------------------------------------
#define BT   64
#define BKS  64                 // k shorts per step
#define BUFS (BT * BKS)         // 4096 shorts = 8 KB

__device__ inline void gld16(const short* g, short* l) {
    __builtin_amdgcn_global_load_lds(
        (const __attribute__((address_space(1))) unsigned int*)g,
        (__attribute__((address_space(3))) unsigned int*)l, 16, 0, 0);
}

template <int V>
__global__ __launch_bounds__(256) void mgemm(
    const short* __restrict__ A, const short* __restrict__ Bt,
    const float* __restrict__ bias, float* __restrict__ C,
    short* __restrict__ Cb, const float* __restrict__ res, int K, int M,
    const int* __restrict__ offs, const float* __restrict__ gatepad,
    const int* __restrict__ tokpad, const int* __restrict__ tmap)
{
    int e, row_lo, row_hi, off_e, bx;
    if (V >= 2) {
        int y = blockIdx.y;
        if (y >= tmap[NTILES]) return;       // beyond active tiles
        int tm = tmap[y];
        e      = tm >> 16;
        row_lo = tm & 0xFFFF;
        off_e  = offs[e];
        row_hi = offs[e + 1];
        if (row_lo >= row_hi) return;
        bx = blockIdx.x;
    } else {
        e = 0; off_e = 0;
        // XCD-aware swizzle: xcd = flat%8 gets contiguous tile band flat/8
        int flat = blockIdx.y * gridDim.x + blockIdx.x;
        int cpx  = (gridDim.x * gridDim.y) >> 3;
        int swz  = (flat & 7) * cpx + (flat >> 3);
        bx = swz % gridDim.x;
        row_lo = (swz / gridDim.x) * BT;
        row_hi = 1 << 30;
    }
    const short* Bte = (V >= 2) ? Bt + (size_t)e * M * K : Bt;
    const float* be  = (V >= 2) ? bias + (size_t)e * M : bias;
    int col0 = bx * BT;

    __shared__ __align__(16) short As[3 * BUFS];   // 24 KB
    __shared__ __align__(16) short Bs[3 * BUFS];   // 24 KB

    int t = threadIdx.x;
    int wave = t >> 6, lane = t & 63;
    int lrow   = lane >> 3;              // 0..7; == row&7 for my staged rows
    int schunk = (lane & 7) ^ lrow;      // inverse-swizzled source 16B chunk

    // staging: call q in {0,1}; row = q*32 + wave*8 + lrow  (row&7 == lrow)
    const short* aQ[2];
    const short* bQ[2];
    #pragma unroll
    for (int q = 0; q < 2; ++q) {
        int row = q * 32 + wave * 8 + lrow;
        int gr = row_lo + row;
        if (V >= 2 && gr >= row_hi) gr = row_lo; // clamp (epilogue guards)
        const short* arow;
        if (V == 2)
            arow = A + (size_t)(tokpad[(e << 12) + ((gr - off_e) & (EPAD - 1))]
                                & (NTOK - 1)) * K;
        else
            arow = A + (size_t)gr * K;
        aQ[q] = arow + (schunk << 3);
        bQ[q] = Bte + (size_t)(col0 + row) * K + (schunk << 3);
    }

    int rin = lane & 15, quad = lane >> 4;
    int wm = (wave & 1) * 32, wn = (wave >> 1) * 32;

    // ---- epilogue operand prefetch (keeps main loop free of stray VMEM) ----
    int cg0 = col0 + wn + rin;
    int cg1 = cg0 + 16;
    float bj[2] = { be[cg0], be[cg1] };
    float resv[2][2][4];
    if (V == 1) {
        #pragma unroll
        for (int i = 0; i < 2; ++i)
            #pragma unroll
            for (int j = 0; j < 2; ++j)
                #pragma unroll
                for (int rr = 0; rr < 4; ++rr)
                    resv[i][j][rr] = res[(size_t)(row_lo + wm + i*16 + quad*4 + rr) * M
                                         + (j ? cg1 : cg0)];
    }
    int   tmv[2][4];
    float tgv[2][4];
    if (V == 3) {
        #pragma unroll
        for (int i = 0; i < 2; ++i)
            #pragma unroll
            for (int rr = 0; rr < 4; ++rr) {
                int rg = row_lo + wm + i*16 + quad*4 + rr;
                int local = (rg - off_e) & (EPAD - 1);
                tmv[i][rr] = tokpad[(e << 12) + local] & (NTOK - 1);
                tgv[i][rr] = gatepad[(e << 12) + local];
            }
    }

    floatx4 acc[2][2];
    #pragma unroll
    for (int i = 0; i < 2; ++i)
        #pragma unroll
        for (int j = 0; j < 2; ++j)
            acc[i][j] = (floatx4){0.f, 0.f, 0.f, 0.f};

    const int NIT = K >> 6;

    // prologue: stage tile 0 -> buf0, tile 1 -> buf1 (8 loads/thread)
    #pragma unroll
    for (int q = 0; q < 2; ++q) {
        gld16(aQ[q], &As[(q * 32 + wave * 8) * BKS]);
        gld16(bQ[q], &Bs[(q * 32 + wave * 8) * BKS]);
    }
    if (NIT > 1) {
        #pragma unroll
        for (int q = 0; q < 2; ++q) {
            gld16(aQ[q] + 64, &As[BUFS + (q * 32 + wave * 8) * BKS]);
            gld16(bQ[q] + 64, &Bs[BUFS + (q * 32 + wave * 8) * BKS]);
        }
        asm volatile("s_waitcnt vmcnt(4)\n\ts_barrier" ::: "memory");
    } else {
        asm volatile("s_waitcnt vmcnt(0)\n\ts_barrier" ::: "memory");
    }
    __builtin_amdgcn_sched_barrier(0);

    int bread = 0;
    for (int it = 0; it < NIT; ++it) {
        if (it + 2 < NIT) {                  // stage tile it+2 (4 loads/thread)
            int bst = bread + 2; if (bst >= 3) bst -= 3;
            int kk = (it + 2) << 6;
            #pragma unroll
            for (int q = 0; q < 2; ++q) {
                gld16(aQ[q] + kk, &As[bst * BUFS + (q * 32 + wave * 8) * BKS]);
                gld16(bQ[q] + kk, &Bs[bst * BUFS + (q * 32 + wave * 8) * BKS]);
            }
        }
        const short* Ab = &As[bread * BUFS];
        const short* Bb = &Bs[bread * BUFS];
        #pragma unroll
        for (int s = 0; s < 2; ++s) {
            bf16x8 af[2], bfr[2];
            #pragma unroll
            for (int i = 0; i < 2; ++i) {
                int row = wm + i * 16 + rin;
                af[i] = *(const bf16x8*)&Ab[row * BKS
                        + ((((s << 2) | quad) ^ (rin & 7)) << 3)];
            }
            #pragma unroll
            for (int j = 0; j < 2; ++j) {
                int row = wn + j * 16 + rin;
                bfr[j] = *(const bf16x8*)&Bb[row * BKS
                        + ((((s << 2) | quad) ^ (rin & 7)) << 3)];
            }
            #pragma unroll
            for (int i = 0; i < 2; ++i)
                #pragma unroll
                for (int j = 0; j < 2; ++j)
                    acc[i][j] = __builtin_amdgcn_mfma_f32_16x16x32_bf16(
                        af[i], bfr[j], acc[i][j], 0, 0, 0);
        }
        if (it + 1 < NIT) {
            if (it + 2 < NIT)
                asm volatile("s_waitcnt vmcnt(4)\n\ts_barrier" ::: "memory");
            else
                asm volatile("s_waitcnt vmcnt(0)\n\ts_barrier" ::: "memory");
            __builtin_amdgcn_sched_barrier(0);
        }
        bread = bread + 1; if (bread >= 3) bread = 0;
    }

    // Epilogue. C/D layout: col = lane&15, row = quad*4 + reg  [m89-verified]
    #pragma unroll
    for (int i = 0; i < 2; ++i) {
        #pragma unroll
        for (int j = 0; j < 2; ++j) {
            int cg = j ? cg1 : cg0;
            #pragma unroll
            for (int rr = 0; rr < 4; ++rr) {
                int rg = row_lo + wm + i * 16 + quad * 4 + rr;
                float val = acc[i][j][rr];
                if (V == 0) {
                    C[(size_t)rg * M + cg] = val + bj[j];
                } else if (V == 1) {
                    C[(size_t)rg * M + cg] = val + bj[j] + resv[i][j][rr];
                } else if (V == 2) {
                    if (rg < row_hi) {
                        float vb_ = val + bj[j];
                        Cb[(size_t)rg * M + cg] = f2bf(vb_ / (1.f + __expf(-vb_)));
                    }
                } else {
                    if (rg < row_hi)
                        unsafeAtomicAdd(&C[(size_t)tmv[i][rr] * M + cg],
                                        tgv[i][rr] * (val + bj[j]));
                }
            }
        }
    }
}

// ---------------------------------------------------------------------------
// Sliding-window attention v4 — occupancy-first (4 blocks/CU), batched
// Q loads (R10-proven) AND batched V loads: 8 V-float2 loads in flight
// ahead of each 8-j FMA chunk (was 1-deep: 64 serialized L2-latency loads).
// Accumulation order per output unchanged (jj ascending) -> numerics
// identical.
// ---------------------------------------------------------------------------
__global__ __launch_bounds__(256, 4) void attn_kernel(
    const float* __restrict__ qkv, const float* __restrict__ sink_ptr,
    short* __restrict__ ao)
{
    __shared__ __align__(16) float KT[32 * KPITCH * 4];   // 35.3 KB
    __shared__ __align__(16) float Ps4[4][64][4];         // 4 KB

    int qblk = blockIdx.x;
    int kvh  = blockIdx.y;
    int q0   = qblk * QB;
    int jbase = q0 - (WS_ - 1);

    int t = threadIdx.x;
    int c4 = (t & 31) * 4, c4g = t & 31;
    for (int r = t >> 5; r < WROWS; r += 8) {
        int j = jbase + r;
        float4 kv4 = make_float4(0.f, 0.f, 0.f, 0.f);
        if (j >= 0)
            kv4 = *(const float4*)(qkv + (size_t)j * QKV_M + KOFF + kvh * HD + c4);
        *(float4*)&KT[(c4g * KPITCH + r) * 4] = kv4;
    }
    __syncthreads();

    int lane = t & 63, wv = t >> 6;
    float sink = sink_ptr[0];
    const float rscale = 0.08838834764831845f;

    int qi = wv;                 // one query per wave
    int i  = q0 + qi;
    bool valid = (jbase + qi + lane) >= 0;

    float sc[4] = {0.f, 0.f, 0.f, 0.f};
    const float* qbase = qkv + (size_t)i * QKV_M + (kvh * 4) * HD;
    #pragma unroll
    for (int cc = 0; cc < 16; ++cc) {
        float4 qv[4][2];
        #pragma unroll
        for (int hh = 0; hh < 4; ++hh)
            #pragma unroll
            for (int k = 0; k < 2; ++k)
                qv[hh][k] = *(const float4*)(qbase + hh * HD + (cc * 2 + k) * 4);
        #pragma unroll
        for (int k = 0; k < 2; ++k) {
            int c = cc * 2 + k;
            float4 kx = *(const float4*)&KT[(c * KPITCH + qi + lane) * 4];
            #pragma unroll
            for (int hh = 0; hh < 4; ++hh)
                sc[hh] += qv[hh][k].x*kx.x + qv[hh][k].y*kx.y
                        + qv[hh][k].z*kx.z + qv[hh][k].w*kx.w;
        }
    }

    float pn[4];
    #pragma unroll
    for (int hh = 0; hh < 4; ++hh) {
        float s = valid ? sc[hh] * rscale : -1e30f;
        float m = s;
        #pragma unroll
        for (int off = 32; off; off >>= 1) m = fmaxf(m, __shfl_xor(m, off, 64));
        float mf = fmaxf(m, sink);
        float p  = __expf(s - mf);
        float ds = p;
        #pragma unroll
        for (int off = 32; off; off >>= 1) ds += __shfl_xor(ds, off, 64);
        pn[hh] = p / (ds + __expf(sink - mf));
    }
    *(float4*)&Ps4[wv][lane][0] = make_float4(pn[0], pn[1], pn[2], pn[3]);

    // PV: V from global, batched 8-deep (8 loads in flight per chunk)
    float o0=0,o1=0,o2=0,o3=0,o4=0,o5=0,o6=0,o7=0;
    const float* vb = qkv + VOFF + (size_t)kvh * HD + 2 * lane;
    #pragma unroll
    for (int jb = 0; jb < 8; ++jb) {
        float2 vv[8];
        #pragma unroll
        for (int k = 0; k < 8; ++k) {
            int rj = jbase + qi + jb * 8 + k;
            rj = rj < 0 ? 0 : rj;             // p=0 there; clamp avoids garbage
            vv[k] = *(const float2*)(vb + (size_t)rj * QKV_M);
        }
        #pragma unroll
        for (int k = 0; k < 8; ++k) {
            float4 p4 = *(const float4*)&Ps4[wv][jb * 8 + k][0];
            o0 += p4.x * vv[k].x; o1 += p4.x * vv[k].y;
            o2 += p4.y * vv[k].x; o3 += p4.y * vv[k].y;
            o4 += p4.z * vv[k].x; o5 += p4.z * vv[k].y;
            o6 += p4.w * vv[k].x; o7 += p4.w * vv[k].y;
        }
    }
    short2 r0; r0.x = f2bf(o0); r0.y = f2bf(o1);
    short2 r1; r1.x = f2bf(o2); r1.y = f2bf(o3);
    short2 r2; r2.x = f2bf(o4); r2.y = f2bf(o5);
    short2 r3; r3.x = f2bf(o6); r3.y = f2bf(o7);
    ((short2*)(ao + (size_t)i * D + (kvh * 4 + 0) * HD))[lane] = r0;
    ((short2*)(ao + (size_t)i * D + (kvh * 4 + 1) * HD))[lane] = r1;
    ((short2*)(ao + (size_t)i * D + (kvh * 4 + 2) * HD))[lane] = r2;
    ((short2*)(ao + (size_t)i * D + (kvh * 4 + 3) * HD))[lane] = r3;
}

// ---------------------------------------------------------------------------
// Fused RMSNorm2 + router + self-scatter, WAVE-PER-TOKEN. Instead of a
// probs[S][16] array, each block writes its 4-token partial expert colsum
// (pcsum[block][16], 32 KB total) — finalize's read shrinks 4x and the
// 128 KB probs traffic disappears.
// ---------------------------------------------------------------------------
__global__ __launch_bounds__(256) void rms_router_kernel(
    const float* __restrict__ x1, const float* __restrict__ w,
    short* __restrict__ h2b, const float* __restrict__ rwT,
    const float* __restrict__ rb, float* __restrict__ pcsum,
    int* __restrict__ ecur, int* __restrict__ tokpad,
    float* __restrict__ gatepad, float* __restrict__ out)
{
    __shared__ float hl[4][D];                     // 16 KB, one row per wave
    __shared__ float wcs[4][E_];
    int t = threadIdx.x, wv = t >> 6, lane = t & 63;
    int tok = blockIdx.x * 4 + wv;

    const float4* xr = (const float4*)(x1 + (size_t)tok * D);
    float4*      orow = (float4*)(out + (size_t)tok * D);
    const float4* wr  = (const float4*)w;
    float4 v[4], wv4[4];
    #pragma unroll
    for (int k = 0; k < 4; ++k) v[k] = xr[lane + 64 * k];
    #pragma unroll
    for (int k = 0; k < 4; ++k) wv4[k] = wr[lane + 64 * k];
    float ss = 0.f;
    #pragma unroll
    for (int k = 0; k < 4; ++k)
        ss += v[k].x*v[k].x + v[k].y*v[k].y + v[k].z*v[k].z + v[k].w*v[k].w;
    #pragma unroll
    for (int off = 32; off; off >>= 1) ss += __shfl_xor(ss, off, 64);
    float scale = rsqrtf(ss * (1.0f / (float)D) + 1e-6f);

    float4* hl4 = (float4*)hl[wv];
    short*  hb  = h2b + (size_t)tok * D;
    #pragma unroll
    for (int k = 0; k < 4; ++k) {
        orow[lane + 64 * k] = v[k];                // out = x1 (FFN added later)
        float4 o;
        o.x = v[k].x * scale * wv4[k].x; o.y = v[k].y * scale * wv4[k].y;
        o.z = v[k].z * scale * wv4[k].z; o.w = v[k].w * scale * wv4[k].w;
        hl4[lane + 64 * k] = o;
        short4 ob;
        ob.x = f2bf(o.x); ob.y = f2bf(o.y); ob.z = f2bf(o.z); ob.w = f2bf(o.w);
        *(short4*)&hb[(lane + 64 * k) * 4] = ob;
    }

    // router dot: lane = e + 16*q; quarter q covers float4 indices q+4i.
    // rwT interleaved: rw4[64*i + lane] is the matching weight float4.
    int q = lane >> 4;
    const float4* rw4 = (const float4*)rwT;
    float part = 0.f;
    #pragma unroll 8
    for (int i = 0; i < 64; ++i) {
        float4 a = hl4[q + 4 * i];                 // broadcast across e-lanes
        float4 b = rw4[64 * i + lane];             // coalesced 1 KB line
        part += a.x * b.x; part += a.y * b.y;
        part += a.z * b.z; part += a.w * b.w;
    }
    part += __shfl_xor(part, 16, 64);
    part += __shfl_xor(part, 32, 64);

    if (lane < E_) {
        float lv = (part + rb[lane]) * 10.0f;      // /0.1

        // lane-parallel argmax (value desc, index asc tie-break = reference)
        float bv = lv; int bi = lane;
        #pragma unroll
        for (int off = 8; off; off >>= 1) {
            float ov = __shfl_xor(bv, off, 16);
            int   oi = __shfl_xor(bi, off, 16);
            if (ov > bv || (ov == bv && oi < bi)) { bv = ov; bi = oi; }
        }
        float lv2 = (lane == bi) ? -3.402823e38f : lv;
        float bv2 = lv2; int bi2 = lane;
        #pragma unroll
        for (int off = 8; off; off >>= 1) {
            float ov = __shfl_xor(bv2, off, 16);
            int   oi = __shfl_xor(bi2, off, 16);
            if (ov > bv2 || (ov == bv2 && oi < bi2)) { bv2 = ov; bi2 = oi; }
        }
        float pexp = __expf(lv - bv);
        float ps = pexp;
        #pragma unroll
        for (int off = 8; off; off >>= 1) ps += __shfl_xor(ps, off, 16);
        wcs[wv][lane] = pexp / ps;                 // per-wave prob row
        if (lane == 0) {
            float e1 = __expf(bv2 - bv);
            float g0 = 1.f / (1.f + e1);
            float g1 = e1 * g0;
            // self-scatter: claim expert-local slots (padded cursors)
            int p0 = atomicAdd(&ecur[bi  * 32], 1) & (EPAD - 1);
            int p1 = atomicAdd(&ecur[bi2 * 32], 1) & (EPAD - 1);
            tokpad[(bi  << 12) + p0] = tok;  gatepad[(bi  << 12) + p0] = g0;
            tokpad[(bi2 << 12) + p1] = tok;  gatepad[(bi2 << 12) + p1] = g1;
        }
    }
    __syncthreads();
    if (t < E_)
        pcsum[blockIdx.x * E_ + t] = wcs[0][t] + wcs[1][t] + wcs[2][t] + wcs[3][t];
}

// ---------------------------------------------------------------------------
// Finalize (single block, tiny): hist from cursors -> offs prefix + tile-map;
// aux from pcsum (32 KB coalesced; (i*256+t)&15 == t&15).
// ---------------------------------------------------------------------------
__global__ __launch_bounds__(256) void finalize_kernel(
    const float* __restrict__ pcsum, const int* __restrict__ ecur,
    int* __restrict__ offs, int* __restrict__ tmap,
    float* __restrict__ aux_out)
{
    __shared__ float csum[E_];
    int t = threadIdx.x;
    if (t < E_) csum[t] = 0.f;
    __syncthreads();

    float part = 0.f;
    for (int i = 0; i < (S / 4) * E_ / 256; ++i)   // 32 iters, coalesced
        part += pcsum[i * 256 + t];
    atomicAdd(&csum[t & 15], part);
    __syncthreads();

    if (t == 0) {
        int acc = 0, nt = 0;
        for (int e = 0; e < E_; ++e) {
            int h = ecur[e * 32];
            offs[e] = acc;
            for (int rb = acc; rb < acc + h; rb += BT)
                tmap[nt++] = (e << 16) | rb;
            acc += h;
        }
        offs[E_] = acc;
        tmap[NTILES] = nt;
        float s = 0.f;
        for (int e = 0; e < E_; ++e) s += csum[e] * csum[e];
        *aux_out = s / (float)E_ * 1e-5f;
    }
}

// ---------------------------------------------------------------------------
extern "C" void kernel_launch(void* const* d_in, const int* in_sizes, int n_in,
                              void* d_out, int out_size, void* d_ws, size_t ws_size,
                              hipStream_t stream)
{
    const float* x        = (const float*)d_in[0];
    const float* norm1_w  = (const float*)d_in[1];
    const float* wq       = (const float*)d_in[2];
    const float* bq       = (const float*)d_in[3];
    const float* wk       = (const float*)d_in[4];
    const float* bk       = (const float*)d_in[5];
    const float* wv       = (const float*)d_in[6];
    const float* bv       = (const float*)d_in[7];
    const float* wo       = (const float*)d_in[8];
    const float* bo       = (const float*)d_in[9];
    const float* sink     = (const float*)d_in[10];
    const float* norm2_w  = (const float*)d_in[11];
    const float* router_w = (const float*)d_in[12];
    const float* router_b = (const float*)d_in[13];
    const float* w1       = (const float*)d_in[14];
    const float* b1       = (const float*)d_in[15];
    const float* w2       = (const float*)d_in[16];
    const float* b2       = (const float*)d_in[17];
    float* out = (float*)d_out;

    // workspace layout
    char* w = (char*)d_ws;
    auto alloc = [&](size_t bytes) {
        char* p = w; w += (bytes + 255) & ~255ull; return p;
    };
    short* wqkvT = (short*)alloc((size_t)QKV_M * D * 2);
    short* woT   = (short*)alloc((size_t)D * D * 2);
    short* w1T   = (short*)alloc((size_t)E_ * HDIM * D * 2);
    short* w2T   = (short*)alloc((size_t)E_ * D * HDIM * 2);
    float* bqkv  = (float*)alloc(QKV_M * 4);
    float* rwT   = (float*)alloc((size_t)E_ * D * 4);
    short* h_bf  = (short*)alloc((size_t)S * D * 2);
    float* qkv   = (float*)alloc((size_t)S * QKV_M * 4);
    float* x1    = (float*)alloc((size_t)S * D * 4);
    short* h2b   = (short*)alloc((size_t)S * D * 2);
    float* pcsum = (float*)alloc((size_t)(S / 4) * E_ * 4);  // 32 KB
    int*   ecur     = (int*)alloc(E_ * 32 * 4);          // padded cursors
    int*   offs     = (int*)alloc(17 * 4);
    int*   tmap     = (int*)alloc((NTILES + 1) * 4);
    int*   tokpad   = (int*)alloc((size_t)E_ * EPAD * 4);
    float* gatepad  = (float*)alloc((size_t)E_ * EPAD * 4);
    // aliases (lifetimes don't overlap):
    short* ao_bf = h_bf;          // h_bf dead after QKV GEMM
    short* hmid  = (short*)qkv;   // qkv dead after attention

    // 0) all weight prep + rmsnorm(x) + cursor zero in one launch
    tconv_all<<<11559, 256, 0, stream>>>(wq, wk, wv, wo, w1, w2, bq, bk, bv,
                                         router_w, wqkvT, woT, w1T, w2T,
                                         bqkv, rwT, x, norm1_w, h_bf, ecur);

    // 1) fused QKV   (24 x 32 = 768 blocks, XCD-swizzled)
    mgemm<0><<<dim3(QKV_M / BT, S / BT), 256, 0, stream>>>(
        h_bf, wqkvT, bqkv, qkv, nullptr, nullptr, D, QKV_M, nullptr, nullptr,
        nullptr, nullptr);

    // 2) attention -> bf16 ao  (512 x 2 = 1024 blocks, 4 blocks/CU)
    attn_kernel<<<dim3(S / QB, NKV), 256, 0, stream>>>(qkv, sink, ao_bf);

    // 3) x1 = x + ao@wo + bo   (16 x 32 = 512 blocks, XCD-swizzled)
    mgemm<1><<<dim3(D / BT, S / BT), 256, 0, stream>>>(
        ao_bf, woT, bo, x1, nullptr, x, D, D, nullptr, nullptr, nullptr,
        nullptr);

    // 4) fused rmsnorm2 + router + self-scatter (wave-per-token)
    rms_router_kernel<<<S / 4, 256, 0, stream>>>(x1, norm2_w, h2b, rwT,
                                                 router_b, pcsum, ecur,
                                                 tokpad, gatepad, out);

    // 5) finalize (tiny): offs prefix + tile-map + aux
    finalize_kernel<<<1, 256, 0, stream>>>(pcsum, ecur, offs, tmap,
                                           out + (size_t)S * D);

    // 6) MoE GEMM1 (tile-map grid; A rows = h2b[tokpad[e][local]])
    mgemm<2><<<dim3(HDIM / BT, NTILES), 256, 0, stream>>>(
        h2b, w1T, b1, nullptr, hmid, nullptr, D, HDIM, offs, gatepad, tokpad,
        tmap);

    // 7) MoE GEMM2 (atomic out[tok] += gate*(val+bias))
    mgemm<3><<<dim3(D / BT, NTILES), 256, 0, stream>>>(
        hmid, w2T, b2, out, nullptr, nullptr, HDIM, D, offs, gatepad, tokpad,
        tmap);
}

// Round 12
// 264.164 us; speedup vs baseline: 1.0217x; 1.0217x over previous
//
#include <hip/hip_runtime.h>
#include <hip/hip_bf16.h>

// Problem constants
#define S     2048
#define D     1024
#define NH    8
#define NKV   2
#define HD    128
#define WS_   64
#define E_    16
#define HDIM  512
#define TOPK  2
#define NTOK  S
#define NSLOT (S*TOPK)         // 4096
#define QKV_M (D + 2*NKV*HD)   // 1536 fused q|k|v columns
#define KOFF  D                // 1024
#define VOFF  (D + NKV*HD)     // 1280
#define QB    4                // queries per attention block
#define WROWS (QB + WS_ - 1)   // 67 key rows per window
#define KPITCH 69              // KT key pitch (float4 units, odd)
#define NTILES 80              // max MoE row-tiles: sum ceil(r_e/64) <= 79
#define EPAD  4096             // per-expert slot-pad (max 2048 actually)

typedef __attribute__((ext_vector_type(8))) short bf16x8;
typedef __attribute__((ext_vector_type(4))) float floatx4;

__device__ inline short f2bf(float f) {
    __hip_bfloat16 b = __float2bfloat16(f);
    return *reinterpret_cast<short*>(&b);
}

// ---------------------------------------------------------------------------
// Small weight prep + attention pre-norm in ONE launch (w1/w2 prep moved
// into the attention dispatch — it has no upstream dependency and rides
// under attn's idle latency slots).
// Regions: [0,512) wq | [512,640) wk | [640,768) wv | [768,1280) wo |
// [1280,1286) bias | [1286,1318) router | 1318 cursor | [1319,3367) rms
// ---------------------------------------------------------------------------
__global__ __launch_bounds__(256) void tconv_all(
    const float* __restrict__ wq, const float* __restrict__ wk,
    const float* __restrict__ wv, const float* __restrict__ wo,
    const float* __restrict__ bq, const float* __restrict__ bk,
    const float* __restrict__ bv, const float* __restrict__ router_w,
    short* __restrict__ wqkvT, short* __restrict__ woT,
    float* __restrict__ bqkv, float* __restrict__ rwT,
    const float* __restrict__ x, const float* __restrict__ norm1_w,
    short* __restrict__ h_bf, int* __restrict__ ecur)
{
    int id = blockIdx.x;
    if (id >= 1319) {                        // 2048 rmsnorm blocks
        int row = id - 1319, t = threadIdx.x;
        float4 v = ((const float4*)(x + (size_t)row * D))[t];
        float ss = v.x*v.x + v.y*v.y + v.z*v.z + v.w*v.w;
        #pragma unroll
        for (int off = 32; off; off >>= 1) ss += __shfl_xor(ss, off, 64);
        __shared__ float red[4];
        if ((t & 63) == 0) red[t >> 6] = ss;
        __syncthreads();
        float total = red[0] + red[1] + red[2] + red[3];
        float scale = rsqrtf(total * (1.0f / (float)D) + 1e-6f);
        float4 wv4 = ((const float4*)norm1_w)[t];
        short4 ob;
        ob.x = f2bf(v.x * scale * wv4.x); ob.y = f2bf(v.y * scale * wv4.y);
        ob.z = f2bf(v.z * scale * wv4.z); ob.w = f2bf(v.w * scale * wv4.w);
        ((short4*)(h_bf + (size_t)row * D))[t] = ob;
        return;
    }
    if (id == 1318) {                        // zero expert cursors (16x32 ints)
        int t = threadIdx.x;
        ecur[t] = 0; ecur[t + 256] = 0;
        return;
    }
    if (id >= 1286) {                        // 32 router_w interleave blocks
        int ky = id - 1286;                  // 0..31
        int t = threadIdx.x;
        int r = t >> 4, c = t & 15;
        int k0 = ky * 32;
        int k1 = k0 + r, k2 = k0 + r + 16;
        rwT[((k1 >> 2) << 6) + (c << 2) + (k1 & 3)] = router_w[k1 * E_ + c];
        rwT[((k2 >> 2) << 6) + (c << 2) + (k2 & 3)] = router_w[k2 * E_ + c];
        return;
    }
    if (id >= 1280) {                        // 6 bias-concat blocks
        int t = (id - 1280) * 256 + threadIdx.x;
        if (t < D) bqkv[t] = bq[t];
        else if (t < VOFF) bqkv[t] = bk[t - D];
        else bqkv[t] = bv[t - VOFF];
        return;
    }
    const float* in; short* outp; int K, M, mx, ky;
    if (id < 512)       { in = wq; outp = wqkvT;                  K = D; M = D;   int l = id;        mx = l & 31; ky = l >> 5; }
    else if (id < 640)  { in = wk; outp = wqkvT + (size_t)KOFF*D; K = D; M = 256; int l = id - 512;  mx = l & 7;  ky = l >> 3; }
    else if (id < 768)  { in = wv; outp = wqkvT + (size_t)VOFF*D; K = D; M = 256; int l = id - 640;  mx = l & 7;  ky = l >> 3; }
    else                { in = wo; outp = woT;                    K = D; M = D;   int l = id - 768;  mx = l & 31; ky = l >> 5; }
    __shared__ float tile[64][33];
    int t = threadIdx.x;
    int k0 = ky * 64, m0 = mx * 32;
    {   // read: 64 rows x 32 floats; 8 threads/row -> 128B segments
        int r = t >> 3, c4 = (t & 7) * 4;
        float4 v0 = *(const float4*)&in[(size_t)(k0 + r) * M + m0 + c4];
        float4 v1 = *(const float4*)&in[(size_t)(k0 + r + 32) * M + m0 + c4];
        tile[r][c4 + 0] = v0.x; tile[r][c4 + 1] = v0.y;
        tile[r][c4 + 2] = v0.z; tile[r][c4 + 3] = v0.w;
        tile[r + 32][c4 + 0] = v1.x; tile[r + 32][c4 + 1] = v1.y;
        tile[r + 32][c4 + 2] = v1.z; tile[r + 32][c4 + 3] = v1.w;
    }
    __syncthreads();
    {   // write: 32 rows x 64 shorts; 16 threads/row -> 128B segments
        int mr = t >> 4, kc4 = (t & 15) * 4;
        short4 o0, o1;
        o0.x = f2bf(tile[kc4 + 0][mr]);      o0.y = f2bf(tile[kc4 + 1][mr]);
        o0.z = f2bf(tile[kc4 + 2][mr]);      o0.w = f2bf(tile[kc4 + 3][mr]);
        o1.x = f2bf(tile[kc4 + 0][mr + 16]); o1.y = f2bf(tile[kc4 + 1][mr + 16]);
        o1.z = f2bf(tile[kc4 + 2][mr + 16]); o1.w = f2bf(tile[kc4 + 3][mr + 16]);
        *(short4*)&outp[(size_t)(m0 + mr) * K + k0 + kc4] = o0;
        *(short4*)&outp[(size_t)(m0 + mr + 16) * K + k0 + kc4] = o1;
    }
}

// ---------------------------------------------------------------------------
// bf16 MFMA GEMM: 64x64 tile, BK=64, TRIPLE-buffered LDS (48 KB),
// global_load_lds width=16 staging issued TWO tiles ahead, raw s_barrier
// with COUNTED s_waitcnt vmcnt(4) (T4). Epilogue operands prefetched into
// registers BEFORE the loop. XOR involution swizzle source+read.
// V<2: XCD-aware block swizzle (T1). MFMA accumulation order identical.
// V=0: C fp32 (QKV)            V=1: +bias+res (WO->x1)
// V=2: MoE1 silu->bf16, A-rows via tokpad[e][local]; tile-map grid
// V=3: MoE2 atomic out[tok] += gate*(val+bias); tile-map grid
// ---------------------------------------------------------------------------
#define BT   64
#define BKS  64                 // k shorts per step
#define BUFS (BT * BKS)         // 4096 shorts = 8 KB

__device__ inline void gld16(const short* g, short* l) {
    __builtin_amdgcn_global_load_lds(
        (const __attribute__((address_space(1))) unsigned int*)g,
        (__attribute__((address_space(3))) unsigned int*)l, 16, 0, 0);
}

template <int V>
__global__ __launch_bounds__(256) void mgemm(
    const short* __restrict__ A, const short* __restrict__ Bt,
    const float* __restrict__ bias, float* __restrict__ C,
    short* __restrict__ Cb, const float* __restrict__ res, int K, int M,
    const int* __restrict__ offs, const float* __restrict__ gatepad,
    const int* __restrict__ tokpad, const int* __restrict__ tmap)
{
    int e, row_lo, row_hi, off_e, bx;
    if (V >= 2) {
        int y = blockIdx.y;
        if (y >= tmap[NTILES]) return;       // beyond active tiles
        int tm = tmap[y];
        e      = tm >> 16;
        row_lo = tm & 0xFFFF;
        off_e  = offs[e];
        row_hi = offs[e + 1];
        if (row_lo >= row_hi) return;
        bx = blockIdx.x;
    } else {
        e = 0; off_e = 0;
        // XCD-aware swizzle: xcd = flat%8 gets contiguous tile band flat/8
        int flat = blockIdx.y * gridDim.x + blockIdx.x;
        int cpx  = (gridDim.x * gridDim.y) >> 3;
        int swz  = (flat & 7) * cpx + (flat >> 3);
        bx = swz % gridDim.x;
        row_lo = (swz / gridDim.x) * BT;
        row_hi = 1 << 30;
    }
    const short* Bte = (V >= 2) ? Bt + (size_t)e * M * K : Bt;
    const float* be  = (V >= 2) ? bias + (size_t)e * M : bias;
    int col0 = bx * BT;

    __shared__ __align__(16) short As[3 * BUFS];   // 24 KB
    __shared__ __align__(16) short Bs[3 * BUFS];   // 24 KB

    int t = threadIdx.x;
    int wave = t >> 6, lane = t & 63;
    int lrow   = lane >> 3;              // 0..7; == row&7 for my staged rows
    int schunk = (lane & 7) ^ lrow;      // inverse-swizzled source 16B chunk

    // staging: call q in {0,1}; row = q*32 + wave*8 + lrow  (row&7 == lrow)
    const short* aQ[2];
    const short* bQ[2];
    #pragma unroll
    for (int q = 0; q < 2; ++q) {
        int row = q * 32 + wave * 8 + lrow;
        int gr = row_lo + row;
        if (V >= 2 && gr >= row_hi) gr = row_lo; // clamp (epilogue guards)
        const short* arow;
        if (V == 2)
            arow = A + (size_t)(tokpad[(e << 12) + ((gr - off_e) & (EPAD - 1))]
                                & (NTOK - 1)) * K;
        else
            arow = A + (size_t)gr * K;
        aQ[q] = arow + (schunk << 3);
        bQ[q] = Bte + (size_t)(col0 + row) * K + (schunk << 3);
    }

    int rin = lane & 15, quad = lane >> 4;
    int wm = (wave & 1) * 32, wn = (wave >> 1) * 32;

    // ---- epilogue operand prefetch (keeps main loop free of stray VMEM) ----
    int cg0 = col0 + wn + rin;
    int cg1 = cg0 + 16;
    float bj[2] = { be[cg0], be[cg1] };
    float resv[2][2][4];
    if (V == 1) {
        #pragma unroll
        for (int i = 0; i < 2; ++i)
            #pragma unroll
            for (int j = 0; j < 2; ++j)
                #pragma unroll
                for (int rr = 0; rr < 4; ++rr)
                    resv[i][j][rr] = res[(size_t)(row_lo + wm + i*16 + quad*4 + rr) * M
                                         + (j ? cg1 : cg0)];
    }
    int   tmv[2][4];
    float tgv[2][4];
    if (V == 3) {
        #pragma unroll
        for (int i = 0; i < 2; ++i)
            #pragma unroll
            for (int rr = 0; rr < 4; ++rr) {
                int rg = row_lo + wm + i*16 + quad*4 + rr;
                int local = (rg - off_e) & (EPAD - 1);
                tmv[i][rr] = tokpad[(e << 12) + local] & (NTOK - 1);
                tgv[i][rr] = gatepad[(e << 12) + local];
            }
    }

    floatx4 acc[2][2];
    #pragma unroll
    for (int i = 0; i < 2; ++i)
        #pragma unroll
        for (int j = 0; j < 2; ++j)
            acc[i][j] = (floatx4){0.f, 0.f, 0.f, 0.f};

    const int NIT = K >> 6;

    // prologue: stage tile 0 -> buf0, tile 1 -> buf1 (8 loads/thread)
    #pragma unroll
    for (int q = 0; q < 2; ++q) {
        gld16(aQ[q], &As[(q * 32 + wave * 8) * BKS]);
        gld16(bQ[q], &Bs[(q * 32 + wave * 8) * BKS]);
    }
    if (NIT > 1) {
        #pragma unroll
        for (int q = 0; q < 2; ++q) {
            gld16(aQ[q] + 64, &As[BUFS + (q * 32 + wave * 8) * BKS]);
            gld16(bQ[q] + 64, &Bs[BUFS + (q * 32 + wave * 8) * BKS]);
        }
        asm volatile("s_waitcnt vmcnt(4)\n\ts_barrier" ::: "memory");
    } else {
        asm volatile("s_waitcnt vmcnt(0)\n\ts_barrier" ::: "memory");
    }
    __builtin_amdgcn_sched_barrier(0);

    int bread = 0;
    for (int it = 0; it < NIT; ++it) {
        if (it + 2 < NIT) {                  // stage tile it+2 (4 loads/thread)
            int bst = bread + 2; if (bst >= 3) bst -= 3;
            int kk = (it + 2) << 6;
            #pragma unroll
            for (int q = 0; q < 2; ++q) {
                gld16(aQ[q] + kk, &As[bst * BUFS + (q * 32 + wave * 8) * BKS]);
                gld16(bQ[q] + kk, &Bs[bst * BUFS + (q * 32 + wave * 8) * BKS]);
            }
        }
        const short* Ab = &As[bread * BUFS];
        const short* Bb = &Bs[bread * BUFS];
        #pragma unroll
        for (int s = 0; s < 2; ++s) {
            bf16x8 af[2], bfr[2];
            #pragma unroll
            for (int i = 0; i < 2; ++i) {
                int row = wm + i * 16 + rin;
                af[i] = *(const bf16x8*)&Ab[row * BKS
                        + ((((s << 2) | quad) ^ (rin & 7)) << 3)];
            }
            #pragma unroll
            for (int j = 0; j < 2; ++j) {
                int row = wn + j * 16 + rin;
                bfr[j] = *(const bf16x8*)&Bb[row * BKS
                        + ((((s << 2) | quad) ^ (rin & 7)) << 3)];
            }
            #pragma unroll
            for (int i = 0; i < 2; ++i)
                #pragma unroll
                for (int j = 0; j < 2; ++j)
                    acc[i][j] = __builtin_amdgcn_mfma_f32_16x16x32_bf16(
                        af[i], bfr[j], acc[i][j], 0, 0, 0);
        }
        if (it + 1 < NIT) {
            if (it + 2 < NIT)
                asm volatile("s_waitcnt vmcnt(4)\n\ts_barrier" ::: "memory");
            else
                asm volatile("s_waitcnt vmcnt(0)\n\ts_barrier" ::: "memory");
            __builtin_amdgcn_sched_barrier(0);
        }
        bread = bread + 1; if (bread >= 3) bread = 0;
    }

    // Epilogue. C/D layout: col = lane&15, row = quad*4 + reg  [m89-verified]
    #pragma unroll
    for (int i = 0; i < 2; ++i) {
        #pragma unroll
        for (int j = 0; j < 2; ++j) {
            int cg = j ? cg1 : cg0;
            #pragma unroll
            for (int rr = 0; rr < 4; ++rr) {
                int rg = row_lo + wm + i * 16 + quad * 4 + rr;
                float val = acc[i][j][rr];
                if (V == 0) {
                    C[(size_t)rg * M + cg] = val + bj[j];
                } else if (V == 1) {
                    C[(size_t)rg * M + cg] = val + bj[j] + resv[i][j][rr];
                } else if (V == 2) {
                    if (rg < row_hi) {
                        float vb_ = val + bj[j];
                        Cb[(size_t)rg * M + cg] = f2bf(vb_ / (1.f + __expf(-vb_)));
                    }
                } else {
                    if (rg < row_hi)
                        unsafeAtomicAdd(&C[(size_t)tmv[i][rr] * M + cg],
                                        tgv[i][rr] * (val + bj[j]));
                }
            }
        }
    }
}

// ---------------------------------------------------------------------------
// Attention + MoE-weight-prep FUSED DISPATCH:
//   blocks [0,1024): sliding-window attention v4 (R10/R11 body, batched
//     Q and V loads, 4 blocks/CU). qblk = bid>>1, kvh = bid&1.
//   blocks [1024,9216): w1/w2 transpose+convert (no upstream dependency —
//     rides under attn's idle latency slots; needed only by MoE GEMM1/2
//     which are 3 dispatches later).
// Shared LDS carve: 38.5 KB (attn KT+Ps4); transpose reuses first 8.3 KB.
// ---------------------------------------------------------------------------
__global__ __launch_bounds__(256, 4) void attn_prep_kernel(
    const float* __restrict__ qkv, const float* __restrict__ sink_ptr,
    short* __restrict__ ao, const float* __restrict__ w1,
    const float* __restrict__ w2, short* __restrict__ w1T,
    short* __restrict__ w2T)
{
    __shared__ __align__(16) float smem[32 * KPITCH * 4 + 4 * 64 * 4]; // 38.5KB

    int bid = blockIdx.x;
    if (bid >= 1024) {
        // ---- w1/w2 transpose+convert (64k x 32m tiles, 128B segments) ----
        int idp = bid - 1024;                // 0..8191
        const float* in; short* outp; int K, M, mx, ky;
        if (idp < 4096) { int e = idp >> 8; int r = idp & 255;
            in = w1 + (size_t)e * D * HDIM; outp = w1T + (size_t)e * D * HDIM;
            K = D; M = HDIM; mx = r & 15; ky = r >> 4; }
        else { int l = idp - 4096; int e = l >> 8; int r = l & 255;
            in = w2 + (size_t)e * D * HDIM; outp = w2T + (size_t)e * D * HDIM;
            K = HDIM; M = D; mx = r & 31; ky = r >> 5; }
        float (*tile)[33] = (float(*)[33])smem;      // 64 x 33 = 8.3 KB
        int t = threadIdx.x;
        int k0 = ky * 64, m0 = mx * 32;
        {
            int r = t >> 3, c4 = (t & 7) * 4;
            float4 v0 = *(const float4*)&in[(size_t)(k0 + r) * M + m0 + c4];
            float4 v1 = *(const float4*)&in[(size_t)(k0 + r + 32) * M + m0 + c4];
            tile[r][c4 + 0] = v0.x; tile[r][c4 + 1] = v0.y;
            tile[r][c4 + 2] = v0.z; tile[r][c4 + 3] = v0.w;
            tile[r + 32][c4 + 0] = v1.x; tile[r + 32][c4 + 1] = v1.y;
            tile[r + 32][c4 + 2] = v1.z; tile[r + 32][c4 + 3] = v1.w;
        }
        __syncthreads();
        {
            int mr = t >> 4, kc4 = (t & 15) * 4;
            short4 o0, o1;
            o0.x = f2bf(tile[kc4 + 0][mr]);      o0.y = f2bf(tile[kc4 + 1][mr]);
            o0.z = f2bf(tile[kc4 + 2][mr]);      o0.w = f2bf(tile[kc4 + 3][mr]);
            o1.x = f2bf(tile[kc4 + 0][mr + 16]); o1.y = f2bf(tile[kc4 + 1][mr + 16]);
            o1.z = f2bf(tile[kc4 + 2][mr + 16]); o1.w = f2bf(tile[kc4 + 3][mr + 16]);
            *(short4*)&outp[(size_t)(m0 + mr) * K + k0 + kc4] = o0;
            *(short4*)&outp[(size_t)(m0 + mr + 16) * K + k0 + kc4] = o1;
        }
        return;
    }

    // ---- attention (R11 body; qblk-major so kvh pairs share the window) ----
    float* KT = smem;                                  // 32*KPITCH*4 floats
    float (*Ps4)[64][4] = (float(*)[64][4])(smem + 32 * KPITCH * 4);

    int qblk = bid >> 1;
    int kvh  = bid & 1;
    int q0   = qblk * QB;
    int jbase = q0 - (WS_ - 1);

    int t = threadIdx.x;
    int c4 = (t & 31) * 4, c4g = t & 31;
    for (int r = t >> 5; r < WROWS; r += 8) {
        int j = jbase + r;
        float4 kv4 = make_float4(0.f, 0.f, 0.f, 0.f);
        if (j >= 0)
            kv4 = *(const float4*)(qkv + (size_t)j * QKV_M + KOFF + kvh * HD + c4);
        *(float4*)&KT[(c4g * KPITCH + r) * 4] = kv4;
    }
    __syncthreads();

    int lane = t & 63, wv = t >> 6;
    float sink = sink_ptr[0];
    const float rscale = 0.08838834764831845f;

    int qi = wv;                 // one query per wave
    int i  = q0 + qi;
    bool valid = (jbase + qi + lane) >= 0;

    float sc[4] = {0.f, 0.f, 0.f, 0.f};
    const float* qbase = qkv + (size_t)i * QKV_M + (kvh * 4) * HD;
    #pragma unroll
    for (int cc = 0; cc < 16; ++cc) {
        float4 qv[4][2];
        #pragma unroll
        for (int hh = 0; hh < 4; ++hh)
            #pragma unroll
            for (int k = 0; k < 2; ++k)
                qv[hh][k] = *(const float4*)(qbase + hh * HD + (cc * 2 + k) * 4);
        #pragma unroll
        for (int k = 0; k < 2; ++k) {
            int c = cc * 2 + k;
            float4 kx = *(const float4*)&KT[(c * KPITCH + qi + lane) * 4];
            #pragma unroll
            for (int hh = 0; hh < 4; ++hh)
                sc[hh] += qv[hh][k].x*kx.x + qv[hh][k].y*kx.y
                        + qv[hh][k].z*kx.z + qv[hh][k].w*kx.w;
        }
    }

    float pn[4];
    #pragma unroll
    for (int hh = 0; hh < 4; ++hh) {
        float s = valid ? sc[hh] * rscale : -1e30f;
        float m = s;
        #pragma unroll
        for (int off = 32; off; off >>= 1) m = fmaxf(m, __shfl_xor(m, off, 64));
        float mf = fmaxf(m, sink);
        float p  = __expf(s - mf);
        float ds = p;
        #pragma unroll
        for (int off = 32; off; off >>= 1) ds += __shfl_xor(ds, off, 64);
        pn[hh] = p / (ds + __expf(sink - mf));
    }
    *(float4*)&Ps4[wv][lane][0] = make_float4(pn[0], pn[1], pn[2], pn[3]);

    // PV: V from global, batched 8-deep (8 loads in flight per chunk)
    float o0=0,o1=0,o2=0,o3=0,o4=0,o5=0,o6=0,o7=0;
    const float* vb = qkv + VOFF + (size_t)kvh * HD + 2 * lane;
    #pragma unroll
    for (int jb = 0; jb < 8; ++jb) {
        float2 vv[8];
        #pragma unroll
        for (int k = 0; k < 8; ++k) {
            int rj = jbase + qi + jb * 8 + k;
            rj = rj < 0 ? 0 : rj;             // p=0 there; clamp avoids garbage
            vv[k] = *(const float2*)(vb + (size_t)rj * QKV_M);
        }
        #pragma unroll
        for (int k = 0; k < 8; ++k) {
            float4 p4 = *(const float4*)&Ps4[wv][jb * 8 + k][0];
            o0 += p4.x * vv[k].x; o1 += p4.x * vv[k].y;
            o2 += p4.y * vv[k].x; o3 += p4.y * vv[k].y;
            o4 += p4.z * vv[k].x; o5 += p4.z * vv[k].y;
            o6 += p4.w * vv[k].x; o7 += p4.w * vv[k].y;
        }
    }
    short2 r0; r0.x = f2bf(o0); r0.y = f2bf(o1);
    short2 r1; r1.x = f2bf(o2); r1.y = f2bf(o3);
    short2 r2; r2.x = f2bf(o4); r2.y = f2bf(o5);
    short2 r3; r3.x = f2bf(o6); r3.y = f2bf(o7);
    ((short2*)(ao + (size_t)i * D + (kvh * 4 + 0) * HD))[lane] = r0;
    ((short2*)(ao + (size_t)i * D + (kvh * 4 + 1) * HD))[lane] = r1;
    ((short2*)(ao + (size_t)i * D + (kvh * 4 + 2) * HD))[lane] = r2;
    ((short2*)(ao + (size_t)i * D + (kvh * 4 + 3) * HD))[lane] = r3;
}

// ---------------------------------------------------------------------------
// Fused RMSNorm2 + router + self-scatter, WAVE-PER-TOKEN (R11-proven).
// ---------------------------------------------------------------------------
__global__ __launch_bounds__(256) void rms_router_kernel(
    const float* __restrict__ x1, const float* __restrict__ w,
    short* __restrict__ h2b, const float* __restrict__ rwT,
    const float* __restrict__ rb, float* __restrict__ pcsum,
    int* __restrict__ ecur, int* __restrict__ tokpad,
    float* __restrict__ gatepad, float* __restrict__ out)
{
    __shared__ float hl[4][D];                     // 16 KB, one row per wave
    __shared__ float wcs[4][E_];
    int t = threadIdx.x, wv = t >> 6, lane = t & 63;
    int tok = blockIdx.x * 4 + wv;

    const float4* xr = (const float4*)(x1 + (size_t)tok * D);
    float4*      orow = (float4*)(out + (size_t)tok * D);
    const float4* wr  = (const float4*)w;
    float4 v[4], wv4[4];
    #pragma unroll
    for (int k = 0; k < 4; ++k) v[k] = xr[lane + 64 * k];
    #pragma unroll
    for (int k = 0; k < 4; ++k) wv4[k] = wr[lane + 64 * k];
    float ss = 0.f;
    #pragma unroll
    for (int k = 0; k < 4; ++k)
        ss += v[k].x*v[k].x + v[k].y*v[k].y + v[k].z*v[k].z + v[k].w*v[k].w;
    #pragma unroll
    for (int off = 32; off; off >>= 1) ss += __shfl_xor(ss, off, 64);
    float scale = rsqrtf(ss * (1.0f / (float)D) + 1e-6f);

    float4* hl4 = (float4*)hl[wv];
    short*  hb  = h2b + (size_t)tok * D;
    #pragma unroll
    for (int k = 0; k < 4; ++k) {
        orow[lane + 64 * k] = v[k];                // out = x1 (FFN added later)
        float4 o;
        o.x = v[k].x * scale * wv4[k].x; o.y = v[k].y * scale * wv4[k].y;
        o.z = v[k].z * scale * wv4[k].z; o.w = v[k].w * scale * wv4[k].w;
        hl4[lane + 64 * k] = o;
        short4 ob;
        ob.x = f2bf(o.x); ob.y = f2bf(o.y); ob.z = f2bf(o.z); ob.w = f2bf(o.w);
        *(short4*)&hb[(lane + 64 * k) * 4] = ob;
    }

    // router dot: lane = e + 16*q; quarter q covers float4 indices q+4i.
    // rwT interleaved: rw4[64*i + lane] is the matching weight float4.
    int q = lane >> 4;
    const float4* rw4 = (const float4*)rwT;
    float part = 0.f;
    #pragma unroll 8
    for (int i = 0; i < 64; ++i) {
        float4 a = hl4[q + 4 * i];                 // broadcast across e-lanes
        float4 b = rw4[64 * i + lane];             // coalesced 1 KB line
        part += a.x * b.x; part += a.y * b.y;
        part += a.z * b.z; part += a.w * b.w;
    }
    part += __shfl_xor(part, 16, 64);
    part += __shfl_xor(part, 32, 64);

    if (lane < E_) {
        float lv = (part + rb[lane]) * 10.0f;      // /0.1

        // lane-parallel argmax (value desc, index asc tie-break = reference)
        float bv = lv; int bi = lane;
        #pragma unroll
        for (int off = 8; off; off >>= 1) {
            float ov = __shfl_xor(bv, off, 16);
            int   oi = __shfl_xor(bi, off, 16);
            if (ov > bv || (ov == bv && oi < bi)) { bv = ov; bi = oi; }
        }
        float lv2 = (lane == bi) ? -3.402823e38f : lv;
        float bv2 = lv2; int bi2 = lane;
        #pragma unroll
        for (int off = 8; off; off >>= 1) {
            float ov = __shfl_xor(bv2, off, 16);
            int   oi = __shfl_xor(bi2, off, 16);
            if (ov > bv2 || (ov == bv2 && oi < bi2)) { bv2 = ov; bi2 = oi; }
        }
        float pexp = __expf(lv - bv);
        float ps = pexp;
        #pragma unroll
        for (int off = 8; off; off >>= 1) ps += __shfl_xor(ps, off, 16);
        wcs[wv][lane] = pexp / ps;                 // per-wave prob row
        if (lane == 0) {
            float e1 = __expf(bv2 - bv);
            float g0 = 1.f / (1.f + e1);
            float g1 = e1 * g0;
            // self-scatter: claim expert-local slots (padded cursors)
            int p0 = atomicAdd(&ecur[bi  * 32], 1) & (EPAD - 1);
            int p1 = atomicAdd(&ecur[bi2 * 32], 1) & (EPAD - 1);
            tokpad[(bi  << 12) + p0] = tok;  gatepad[(bi  << 12) + p0] = g0;
            tokpad[(bi2 << 12) + p1] = tok;  gatepad[(bi2 << 12) + p1] = g1;
        }
    }
    __syncthreads();
    if (t < E_)
        pcsum[blockIdx.x * E_ + t] = wcs[0][t] + wcs[1][t] + wcs[2][t] + wcs[3][t];
}

// ---------------------------------------------------------------------------
// Finalize (single block, tiny): hist from cursors -> offs prefix + tile-map;
// aux from pcsum (32 KB coalesced).
// ---------------------------------------------------------------------------
__global__ __launch_bounds__(256) void finalize_kernel(
    const float* __restrict__ pcsum, const int* __restrict__ ecur,
    int* __restrict__ offs, int* __restrict__ tmap,
    float* __restrict__ aux_out)
{
    __shared__ float csum[E_];
    int t = threadIdx.x;
    if (t < E_) csum[t] = 0.f;
    __syncthreads();

    float part = 0.f;
    for (int i = 0; i < (S / 4) * E_ / 256; ++i)   // 32 iters, coalesced
        part += pcsum[i * 256 + t];
    atomicAdd(&csum[t & 15], part);
    __syncthreads();

    if (t == 0) {
        int acc = 0, nt = 0;
        for (int e = 0; e < E_; ++e) {
            int h = ecur[e * 32];
            offs[e] = acc;
            for (int rb = acc; rb < acc + h; rb += BT)
                tmap[nt++] = (e << 16) | rb;
            acc += h;
        }
        offs[E_] = acc;
        tmap[NTILES] = nt;
        float s = 0.f;
        for (int e = 0; e < E_; ++e) s += csum[e] * csum[e];
        *aux_out = s / (float)E_ * 1e-5f;
    }
}

// ---------------------------------------------------------------------------
extern "C" void kernel_launch(void* const* d_in, const int* in_sizes, int n_in,
                              void* d_out, int out_size, void* d_ws, size_t ws_size,
                              hipStream_t stream)
{
    const float* x        = (const float*)d_in[0];
    const float* norm1_w  = (const float*)d_in[1];
    const float* wq       = (const float*)d_in[2];
    const float* bq       = (const float*)d_in[3];
    const float* wk       = (const float*)d_in[4];
    const float* bk       = (const float*)d_in[5];
    const float* wv       = (const float*)d_in[6];
    const float* bv       = (const float*)d_in[7];
    const float* wo       = (const float*)d_in[8];
    const float* bo       = (const float*)d_in[9];
    const float* sink     = (const float*)d_in[10];
    const float* norm2_w  = (const float*)d_in[11];
    const float* router_w = (const float*)d_in[12];
    const float* router_b = (const float*)d_in[13];
    const float* w1       = (const float*)d_in[14];
    const float* b1       = (const float*)d_in[15];
    const float* w2       = (const float*)d_in[16];
    const float* b2       = (const float*)d_in[17];
    float* out = (float*)d_out;

    // workspace layout
    char* w = (char*)d_ws;
    auto alloc = [&](size_t bytes) {
        char* p = w; w += (bytes + 255) & ~255ull; return p;
    };
    short* wqkvT = (short*)alloc((size_t)QKV_M * D * 2);
    short* woT   = (short*)alloc((size_t)D * D * 2);
    short* w1T   = (short*)alloc((size_t)E_ * HDIM * D * 2);
    short* w2T   = (short*)alloc((size_t)E_ * D * HDIM * 2);
    float* bqkv  = (float*)alloc(QKV_M * 4);
    float* rwT   = (float*)alloc((size_t)E_ * D * 4);
    short* h_bf  = (short*)alloc((size_t)S * D * 2);
    float* qkv   = (float*)alloc((size_t)S * QKV_M * 4);
    float* x1    = (float*)alloc((size_t)S * D * 4);
    short* h2b   = (short*)alloc((size_t)S * D * 2);
    float* pcsum = (float*)alloc((size_t)(S / 4) * E_ * 4);  // 32 KB
    int*   ecur     = (int*)alloc(E_ * 32 * 4);          // padded cursors
    int*   offs     = (int*)alloc(17 * 4);
    int*   tmap     = (int*)alloc((NTILES + 1) * 4);
    int*   tokpad   = (int*)alloc((size_t)E_ * EPAD * 4);
    float* gatepad  = (float*)alloc((size_t)E_ * EPAD * 4);
    // aliases (lifetimes don't overlap):
    short* ao_bf = h_bf;          // h_bf dead after QKV GEMM
    short* hmid  = (short*)qkv;   // qkv dead after attention

    // 0) small weight prep + rmsnorm(x) + cursor zero (w1/w2 prep deferred)
    tconv_all<<<3367, 256, 0, stream>>>(wq, wk, wv, wo, bq, bk, bv,
                                        router_w, wqkvT, woT, bqkv, rwT,
                                        x, norm1_w, h_bf, ecur);

    // 1) fused QKV   (24 x 32 = 768 blocks, XCD-swizzled)
    mgemm<0><<<dim3(QKV_M / BT, S / BT), 256, 0, stream>>>(
        h_bf, wqkvT, bqkv, qkv, nullptr, nullptr, D, QKV_M, nullptr, nullptr,
        nullptr, nullptr);

    // 2) attention + w1/w2 prep in ONE dispatch (1024 attn + 8192 prep blocks)
    attn_prep_kernel<<<9216, 256, 0, stream>>>(qkv, sink, ao_bf,
                                               w1, w2, w1T, w2T);

    // 3) x1 = x + ao@wo + bo   (16 x 32 = 512 blocks, XCD-swizzled)
    mgemm<1><<<dim3(D / BT, S / BT), 256, 0, stream>>>(
        ao_bf, woT, bo, x1, nullptr, x, D, D, nullptr, nullptr, nullptr,
        nullptr);

    // 4) fused rmsnorm2 + router + self-scatter (wave-per-token)
    rms_router_kernel<<<S / 4, 256, 0, stream>>>(x1, norm2_w, h2b, rwT,
                                                 router_b, pcsum, ecur,
                                                 tokpad, gatepad, out);

    // 5) finalize (tiny): offs prefix + tile-map + aux
    finalize_kernel<<<1, 256, 0, stream>>>(pcsum, ecur, offs, tmap,
                                           out + (size_t)S * D);

    // 6) MoE GEMM1 (tile-map grid; A rows = h2b[tokpad[e][local]])
    mgemm<2><<<dim3(HDIM / BT, NTILES), 256, 0, stream>>>(
        h2b, w1T, b1, nullptr, hmid, nullptr, D, HDIM, offs, gatepad, tokpad,
        tmap);

    // 7) MoE GEMM2 (atomic out[tok] += gate*(val+bias))
    mgemm<3><<<dim3(D / BT, NTILES), 256, 0, stream>>>(
        hmid, w2T, b2, out, nullptr, nullptr, HDIM, D, offs, gatepad, tokpad,
        tmap);
}